// Round 13
// baseline (311.712 us; speedup 1.0000x reference)
//
#include <hip/hip_runtime.h>
#include <stdint.h>

#define N_NODES 262144
#define N_EDGES 4194304
#define N_GRAPHS 1024
#define IN_DIM 10
#define HIDDEN 32
#define NBUCKET 1024          // bucket b owns dst nodes [b*256, b*256+256)
#define NSUB 8                // per-XCD sub-buckets (j = blockIdx.x & 7)
#define CAP_SUB 704           // max edges/sub-bucket (mean 512, +8.5 sigma)
#define BROW (NSUB * CAP_SUB) // arena row stride per bucket = 5632
#define STG_CAP BROW
#define S_EDGES 16384         // edges per passA block
#define PA_BLOCKS (N_EDGES / S_EDGES)   // 256
#define PA_THREADS 512

typedef int i4v __attribute__((ext_vector_type(4)));

__device__ __forceinline__ float fatomic_add(float* p, float v) {
    return unsafeAtomicAdd(p, v);   // HW global_atomic_add_f32
}

__device__ __forceinline__ uint16_t f2bf(float f) {          // RNE f32->bf16
    uint32_t u = __float_as_uint(f);
    u = (u + 0x7FFF + ((u >> 16) & 1)) >> 16;
    return (uint16_t)u;
}
__device__ __forceinline__ float bf_lo(uint32_t w) { return __uint_as_float(w << 16); }
__device__ __forceinline__ float bf_hi(uint32_t w) { return __uint_as_float(w & 0xFFFF0000u); }

// ---- pass A: block-staged two-phase partition into per-XCD dst-sub-buckets --
// src/dst streamed with non-temporal loads (no reuse; keep L2 clean).

__global__ __launch_bounds__(PA_THREADS) void passA(const int* __restrict__ src,
                                                    const int* __restrict__ dst,
                                                    int* __restrict__ bcnt,
                                                    uint32_t* __restrict__ arena) {
    __shared__ int hist[NBUCKET];
    __shared__ int cur[NBUCKET];
    int blk = blockIdx.x, t = threadIdx.x;
    int j = blk & (NSUB - 1);
    size_t e0 = (size_t)blk * S_EDGES;

    for (int k = t; k < NBUCKET; k += PA_THREADS) hist[k] = 0;
    __syncthreads();

    const i4v* dp = reinterpret_cast<const i4v*>(dst + e0);
    const i4v* sp = reinterpret_cast<const i4v*>(src + e0);

    for (int k = t; k < S_EDGES / 4; k += PA_THREADS) {
        i4v d4 = __builtin_nontemporal_load(dp + k);
        atomicAdd(&hist[d4.x >> 8], 1);
        atomicAdd(&hist[d4.y >> 8], 1);
        atomicAdd(&hist[d4.z >> 8], 1);
        atomicAdd(&hist[d4.w >> 8], 1);
    }
    __syncthreads();

    for (int k = t; k < NBUCKET; k += PA_THREADS) {
        int h = hist[k];
        cur[k] = (h > 0) ? atomicAdd(&bcnt[(k * NSUB + j) * 16], h) : 0;
    }
    __syncthreads();

    for (int k = t; k < S_EDGES / 4; k += PA_THREADS) {
        i4v d4 = __builtin_nontemporal_load(dp + k);
        i4v s4 = __builtin_nontemporal_load(sp + k);
        {
            int d = d4.x, b = d >> 8;
            int pos = atomicAdd(&cur[b], 1);
            if (pos < CAP_SUB)
                arena[(size_t)(b * NSUB + j) * CAP_SUB + pos] = ((uint32_t)(d & 255) << 18) | (uint32_t)s4.x;
        }
        {
            int d = d4.y, b = d >> 8;
            int pos = atomicAdd(&cur[b], 1);
            if (pos < CAP_SUB)
                arena[(size_t)(b * NSUB + j) * CAP_SUB + pos] = ((uint32_t)(d & 255) << 18) | (uint32_t)s4.y;
        }
        {
            int d = d4.z, b = d >> 8;
            int pos = atomicAdd(&cur[b], 1);
            if (pos < CAP_SUB)
                arena[(size_t)(b * NSUB + j) * CAP_SUB + pos] = ((uint32_t)(d & 255) << 18) | (uint32_t)s4.z;
        }
        {
            int d = d4.w, b = d >> 8;
            int pos = atomicAdd(&cur[b], 1);
            if (pos < CAP_SUB)
                arena[(size_t)(b * NSUB + j) * CAP_SUB + pos] = ((uint32_t)(d & 255) << 18) | (uint32_t)s4.w;
        }
    }
}

// ---- bucket-local counting sort (LDS) + dinv + bf16 xs prescale -------------
// Emits block-local degree-sorted permutation:
//   binfo2[b*256 + g*64 + slot] = nib<<23 | beg<<10 | len   (nib in [0,64))

__global__ void bucket_sort(uint32_t* __restrict__ arena, const int* __restrict__ bcnt,
                            const float* __restrict__ x, float* __restrict__ dinv,
                            uint32_t* __restrict__ binfo2, uint16_t* __restrict__ xs) {
    __shared__ uint32_t stg[STG_CAP];
    __shared__ int scnt[NSUB];
    __shared__ int h[256];
    __shared__ int cur[256];
    __shared__ float dsh[256];
    __shared__ int dh[256];                       // 4 groups x 64 degree bins
    int b = blockIdx.x, t = threadIdx.x;
    int base = b * 256;
    if (t < NSUB) {
        int c = bcnt[(b * NSUB + t) * 16];
        scnt[t] = (c > CAP_SUB) ? CAP_SUB : c;
    }
    h[t] = 0;
    dh[t] = 0;
    __syncthreads();
    int off = 0;
    #pragma unroll
    for (int j = 0; j < NSUB; ++j) {
        int len = scnt[j];
        const uint32_t* sp = arena + (size_t)(b * NSUB + j) * CAP_SUB;
        for (int k = t; k < len; k += 256) stg[off + k] = __builtin_nontemporal_load(sp + k);
        off += len;
    }
    int nb = off;
    __syncthreads();
    for (int k = t; k < nb; k += 256) atomicAdd(&h[stg[k] >> 18], 1);
    __syncthreads();
    int myh = h[t];
    #pragma unroll
    for (int o = 1; o < 256; o <<= 1) {
        int v = (t >= o) ? h[t - o] : 0;
        __syncthreads();
        h[t] += v;
        __syncthreads();
    }
    int excl = h[t] - myh;
    float dv = rsqrtf(1.0f + (float)myh);           // +1 self-loop
    dinv[base + t] = dv;
    dsh[t] = dv;
    cur[t] = excl;
    // group-local (64-node) degree histogram; group g64 = t>>6 = wave id
    int g64 = t >> 6, lane = t & 63;
    int dbin = (myh > 63) ? 63 : myh;
    atomicAdd(&dh[g64 * 64 + dbin], 1);
    __syncthreads();
    {   // each wave scans its own group's 64 bins (exclusive)
        int v = dh[g64 * 64 + lane];
        int inc = v;
        #pragma unroll
        for (int o = 1; o < 64; o <<= 1) {
            int u = __shfl_up(inc, o);
            if (lane >= o) inc += u;
        }
        dh[g64 * 64 + lane] = inc - v;
    }
    __syncthreads();
    {
        int slot = atomicAdd(&dh[g64 * 64 + dbin], 1);   // rank within group
        int lc = (myh > 1023) ? 1023 : myh;
        binfo2[base + g64 * 64 + slot] =
            ((uint32_t)lane << 23) | ((uint32_t)excl << 10) | (uint32_t)lc;
    }
    uint32_t* wp = arena + (size_t)b * BROW;
    for (int k = t; k < nb; k += 256) {
        uint32_t w = stg[k];
        int d = w >> 18;
        int pos = atomicAdd(&cur[d], 1);
        wp[pos] = w & 0x3FFFF;
    }
    // fused bf16 prescale
    for (int idx = t; idx < 256 * 16; idx += 256) {
        int n = idx >> 4, k = idx & 15;
        float val = (k < IN_DIM) ? x[(size_t)(base + n) * IN_DIM + k] * dsh[n] : 0.0f;
        xs[(size_t)(base + n) * 16 + k] = f2bf(val);
    }
}

// ---- fused layer 1: gather xs + dense W1 + ReLU -> zs (bf16) ----------------
// block = 256 thr = 64 nodes; edge words non-temporal, xs gathers cached.

__global__ void agg1_dense1(const uint16_t* __restrict__ xs, const uint32_t* __restrict__ arena,
                            const uint32_t* __restrict__ binfo2, const float* __restrict__ dinv,
                            const float* __restrict__ W1, const float* __restrict__ b1,
                            uint16_t* __restrict__ zs) {
    __shared__ float ash[64 * 12];
    __shared__ float w[IN_DIM * HIDDEN];
    int t = threadIdx.x;
    int base = blockIdx.x * 64;
    for (int j = t; j < IN_DIM * HIDDEN; j += 256) w[j] = W1[j];

    int idx = t >> 2;                                 // slot 0..63 (degree-sorted)
    uint32_t wrd = __builtin_nontemporal_load(binfo2 + base + idx);
    int nib = (int)(wrd >> 23);                       // 0..63, block-local
    int beg = (int)((wrd >> 10) & 0x1FFF);
    int len = (int)(wrd & 0x3FF);
    int n = base + nib;
    int q = t & 1, g = (t >> 1) & 1;
    const uint32_t* ep = arena + (size_t)(n >> 8) * BROW + beg;
    const uint4* Xv = reinterpret_cast<const uint4*>(xs);   // 2 uint4/row
    float a[8];
    #pragma unroll
    for (int j = 0; j < 8; ++j) a[j] = 0.0f;
    if (g == 0) {                                           // self-loop
        uint4 v = Xv[(size_t)n * 2 + q];
        a[0] += bf_lo(v.x); a[1] += bf_hi(v.x);
        a[2] += bf_lo(v.y); a[3] += bf_hi(v.y);
        a[4] += bf_lo(v.z); a[5] += bf_hi(v.z);
        a[6] += bf_lo(v.w); a[7] += bf_hi(v.w);
    }
    for (int i = g; i < len; i += 2) {
        int si = (int)__builtin_nontemporal_load(ep + i);
        uint4 v = Xv[(size_t)si * 2 + q];
        a[0] += bf_lo(v.x); a[1] += bf_hi(v.x);
        a[2] += bf_lo(v.y); a[3] += bf_hi(v.y);
        a[4] += bf_lo(v.z); a[5] += bf_hi(v.z);
        a[6] += bf_lo(v.w); a[7] += bf_hi(v.w);
    }
    #pragma unroll
    for (int j = 0; j < 8; ++j) a[j] += __shfl_xor(a[j], 2);
    if (g == 0) {
        if (q == 0) {
            #pragma unroll
            for (int j = 0; j < 8; ++j) ash[nib * 12 + j] = a[j];
        } else {
            #pragma unroll
            for (int j = 0; j < 4; ++j) ash[nib * 12 + 8 + j] = a[j];  // cols 8..11
        }
    }
    __syncthreads();

    // dense: thread t -> node t>>2 (natural order), col-oct (t&3)*8
    int dn_i = t >> 2, c0 = (t & 3) * 8;
    int node = base + dn_i;
    float s[8];
    #pragma unroll
    for (int j = 0; j < 8; ++j) s[j] = 0.0f;
    #pragma unroll
    for (int k = 0; k < IN_DIM; ++k) {
        float ak = ash[dn_i * 12 + k];
        #pragma unroll
        for (int j = 0; j < 8; ++j) s[j] += ak * w[k * HIDDEN + c0 + j];
    }
    float dvv = dinv[node];
    uint32_t pk[4];
    #pragma unroll
    for (int j = 0; j < 4; ++j) {
        float v0 = fmaxf(dvv * s[2 * j] + b1[c0 + 2 * j], 0.0f) * dvv;
        float v1 = fmaxf(dvv * s[2 * j + 1] + b1[c0 + 2 * j + 1], 0.0f) * dvv;
        pk[j] = (uint32_t)f2bf(v0) | ((uint32_t)f2bf(v1) << 16);
    }
    reinterpret_cast<uint4*>(zs)[(size_t)node * 4 + (t & 3)] =
        make_uint4(pk[0], pk[1], pk[2], pk[3]);
}

// ---- fused layer 2: gather zs + dense W2 + ReLU + run-reduce pool -----------
// block = 256 thr = 64 nodes; edge words non-temporal, zs gathers cached.

__global__ void agg2_dense2_pool(const uint16_t* __restrict__ zs, const uint32_t* __restrict__ arena,
                                 const uint32_t* __restrict__ binfo2, const float* __restrict__ dinv,
                                 const float* __restrict__ W2, const float* __restrict__ b2,
                                 const int* __restrict__ batch, float* __restrict__ pooled) {
    __shared__ float vsh[64 * 33];
    __shared__ float w[HIDDEN * HIDDEN];
    __shared__ int bsh[64];
    int t = threadIdx.x;
    int base = blockIdx.x * 64;
    for (int j = t; j < HIDDEN * HIDDEN; j += 256) w[j] = W2[j];
    if (t < 64) bsh[t] = batch[base + t];

    int idx = t >> 2;                                 // slot 0..63 (degree-sorted)
    uint32_t wrd = __builtin_nontemporal_load(binfo2 + base + idx);
    int nib = (int)(wrd >> 23);                       // 0..63, block-local
    int beg = (int)((wrd >> 10) & 0x1FFF);
    int len = (int)(wrd & 0x3FF);
    int n = base + nib;
    int q = t & 3;
    const uint32_t* ep = arena + (size_t)(n >> 8) * BROW + beg;
    const uint4* Zv = reinterpret_cast<const uint4*>(zs);   // 4 uint4/row
    float a[8];
    {                                                       // self-loop init
        uint4 v = Zv[(size_t)n * 4 + q];
        a[0] = bf_lo(v.x); a[1] = bf_hi(v.x);
        a[2] = bf_lo(v.y); a[3] = bf_hi(v.y);
        a[4] = bf_lo(v.z); a[5] = bf_hi(v.z);
        a[6] = bf_lo(v.w); a[7] = bf_hi(v.w);
    }
    for (int i = 0; i < len; ++i) {
        int si = (int)__builtin_nontemporal_load(ep + i);
        uint4 v = Zv[(size_t)si * 4 + q];
        a[0] += bf_lo(v.x); a[1] += bf_hi(v.x);
        a[2] += bf_lo(v.y); a[3] += bf_hi(v.y);
        a[4] += bf_lo(v.z); a[5] += bf_hi(v.z);
        a[6] += bf_lo(v.w); a[7] += bf_hi(v.w);
    }
    #pragma unroll
    for (int j = 0; j < 8; ++j) vsh[nib * 33 + q * 8 + j] = a[j];
    __syncthreads();

    // dense: thread t -> node t>>2 (natural order), col-oct (t&3)*8
    int dn_i = t >> 2, c0 = (t & 3) * 8;
    int node = base + dn_i;
    float s[8];
    #pragma unroll
    for (int j = 0; j < 8; ++j) s[j] = 0.0f;
    #pragma unroll
    for (int k = 0; k < HIDDEN; ++k) {
        float ak = vsh[dn_i * 33 + k];
        #pragma unroll
        for (int j = 0; j < 8; ++j) s[j] += ak * w[k * HIDDEN + c0 + j];
    }
    float dvv = dinv[node];
    float v[8];
    #pragma unroll
    for (int j = 0; j < 8; ++j) v[j] = fmaxf(dvv * s[j] + b2[c0 + j], 0.0f);
    __syncthreads();
    #pragma unroll
    for (int j = 0; j < 8; ++j) vsh[dn_i * 33 + c0 + j] = v[j];
    __syncthreads();

    // run-reduce pool: col = t&31, segment t>>5 covers 8 nodes (batch sorted)
    int col = t & 31, seg = t >> 5;
    int r0 = seg * 8;
    float run = vsh[r0 * 33 + col];
    int cur = bsh[r0];
    #pragma unroll
    for (int j = 1; j < 8; ++j) {
        int bg = bsh[r0 + j];
        float vv = vsh[(r0 + j) * 33 + col];
        if (bg == cur) run += vv;
        else {
            fatomic_add(&pooled[(size_t)cur * HIDDEN + col], run);
            run = vv;
            cur = bg;
        }
    }
    fatomic_add(&pooled[(size_t)cur * HIDDEN + col], run);
}

// ---- final linear (graph counts via binary search on sorted batch) ----------

__global__ void final_k(const float* __restrict__ pooled, const int* __restrict__ batch,
                        const float* __restrict__ Wlin, const float* __restrict__ blin,
                        float* __restrict__ out) {
    int g = blockIdx.x * blockDim.x + threadIdx.x;
    if (g < N_GRAPHS) {
        int lo = 0, hi = N_NODES;
        while (lo < hi) { int mid = (lo + hi) >> 1; if (batch[mid] < g) lo = mid + 1; else hi = mid; }
        int first = lo;
        lo = 0; hi = N_NODES;
        while (lo < hi) { int mid = (lo + hi) >> 1; if (batch[mid] <= g) lo = mid + 1; else hi = mid; }
        float cc = (float)(lo - first);
        if (cc < 1.0f) cc = 1.0f;
        float s = 0.0f;
        #pragma unroll
        for (int c = 0; c < HIDDEN; ++c) s += pooled[(size_t)g * HIDDEN + c] * Wlin[c];
        out[g] = s / cc + blin[0];
    }
}

// ---- launch -------------------------------------------------------------------

extern "C" void kernel_launch(void* const* d_in, const int* in_sizes, int n_in,
                              void* d_out, int out_size, void* d_ws, size_t ws_size,
                              hipStream_t stream) {
    const float* x     = (const float*)d_in[0];
    const int*   ei    = (const int*)d_in[1];
    const int*   batch = (const int*)d_in[2];
    const float* W1    = (const float*)d_in[3];
    const float* b1    = (const float*)d_in[4];
    const float* W2    = (const float*)d_in[5];
    const float* b2    = (const float*)d_in[6];
    const float* Wlin  = (const float*)d_in[7];
    const float* blin  = (const float*)d_in[8];
    float* out = (float*)d_out;

    const int* src = ei;
    const int* dst = ei + N_EDGES;

    const size_t N = N_NODES;
    float*    F      = (float*)d_ws;
    uint16_t* zs     = (uint16_t*)F;                       // 32 bf16/node = 8N words
    uint16_t* xs     = (uint16_t*)(F + 8 * N);             // 16 bf16/node = 8N words
    float*    dinv   = F + 16 * N;                         // N
    uint32_t* binfo2 = (uint32_t*)(dinv + N);              // N
    int*      bcnt   = (int*)(binfo2 + N);                 // 1024*8*16  -- zeroed
    float*    pooled = (float*)(bcnt + NBUCKET * NSUB * 16); // G*32     -- zeroed
    uint32_t* arena  = (uint32_t*)(pooled + (size_t)N_GRAPHS * HIDDEN); // NBUCKET*BROW

    size_t zbytes = ((size_t)NBUCKET * NSUB * 16 + (size_t)N_GRAPHS * HIDDEN) * sizeof(int);
    hipMemsetAsync(bcnt, 0, zbytes, stream);

    passA<<<PA_BLOCKS, PA_THREADS, 0, stream>>>(src, dst, bcnt, arena);
    bucket_sort<<<NBUCKET, 256, 0, stream>>>(arena, bcnt, x, dinv, binfo2, xs);
    agg1_dense1<<<N_NODES / 64, 256, 0, stream>>>(xs, arena, binfo2, dinv, W1, b1, zs);
    agg2_dense2_pool<<<N_NODES / 64, 256, 0, stream>>>(zs, arena, binfo2, dinv, W2, b2, batch, pooled);
    final_k<<<(N_GRAPHS + 255) / 256, 256, 0, stream>>>(pooled, batch, Wlin, blin, out);
}

// Round 14
// 245.976 us; speedup vs baseline: 1.2672x; 1.2672x over previous
//
#include <hip/hip_runtime.h>
#include <stdint.h>

#define N_NODES 262144
#define N_EDGES 4194304
#define N_GRAPHS 1024
#define IN_DIM 10
#define HIDDEN 32
#define NBUCKET 1024          // bucket b owns dst nodes [b*256, b*256+256)
#define NSUB 8                // per-XCD sub-buckets (j = blockIdx.x & 7)
#define CAP_SUB 704           // max edges/sub-bucket (mean 512, +8.5 sigma)
#define BROW (NSUB * CAP_SUB) // arena row stride per bucket = 5632
#define STG_CAP BROW
#define S_EDGES 16384         // edges per passA block
#define PA_BLOCKS (N_EDGES / S_EDGES)   // 256
#define PA_THREADS 512

__device__ __forceinline__ float fatomic_add(float* p, float v) {
    return unsafeAtomicAdd(p, v);   // HW global_atomic_add_f32
}

__device__ __forceinline__ uint16_t f2bf(float f) {          // RNE f32->bf16
    uint32_t u = __float_as_uint(f);
    u = (u + 0x7FFF + ((u >> 16) & 1)) >> 16;
    return (uint16_t)u;
}
__device__ __forceinline__ float bf_lo(uint32_t w) { return __uint_as_float(w << 16); }
__device__ __forceinline__ float bf_hi(uint32_t w) { return __uint_as_float(w & 0xFFFF0000u); }

// ---- pass A: block-staged two-phase partition into per-XCD dst-sub-buckets --

__global__ __launch_bounds__(PA_THREADS) void passA(const int* __restrict__ src,
                                                    const int* __restrict__ dst,
                                                    int* __restrict__ bcnt,
                                                    uint32_t* __restrict__ arena) {
    __shared__ int hist[NBUCKET];
    __shared__ int cur[NBUCKET];
    int blk = blockIdx.x, t = threadIdx.x;
    int j = blk & (NSUB - 1);
    size_t e0 = (size_t)blk * S_EDGES;

    for (int k = t; k < NBUCKET; k += PA_THREADS) hist[k] = 0;
    __syncthreads();

    const int4* dp = reinterpret_cast<const int4*>(dst + e0);
    const int4* sp = reinterpret_cast<const int4*>(src + e0);

    for (int k = t; k < S_EDGES / 4; k += PA_THREADS) {
        int4 d4 = dp[k];
        atomicAdd(&hist[d4.x >> 8], 1);
        atomicAdd(&hist[d4.y >> 8], 1);
        atomicAdd(&hist[d4.z >> 8], 1);
        atomicAdd(&hist[d4.w >> 8], 1);
    }
    __syncthreads();

    for (int k = t; k < NBUCKET; k += PA_THREADS) {
        int h = hist[k];
        cur[k] = (h > 0) ? atomicAdd(&bcnt[(k * NSUB + j) * 16], h) : 0;
    }
    __syncthreads();

    for (int k = t; k < S_EDGES / 4; k += PA_THREADS) {
        int4 d4 = dp[k];
        int4 s4 = sp[k];
        {
            int d = d4.x, b = d >> 8;
            int pos = atomicAdd(&cur[b], 1);
            if (pos < CAP_SUB)
                arena[(size_t)(b * NSUB + j) * CAP_SUB + pos] = ((uint32_t)(d & 255) << 18) | (uint32_t)s4.x;
        }
        {
            int d = d4.y, b = d >> 8;
            int pos = atomicAdd(&cur[b], 1);
            if (pos < CAP_SUB)
                arena[(size_t)(b * NSUB + j) * CAP_SUB + pos] = ((uint32_t)(d & 255) << 18) | (uint32_t)s4.y;
        }
        {
            int d = d4.z, b = d >> 8;
            int pos = atomicAdd(&cur[b], 1);
            if (pos < CAP_SUB)
                arena[(size_t)(b * NSUB + j) * CAP_SUB + pos] = ((uint32_t)(d & 255) << 18) | (uint32_t)s4.z;
        }
        {
            int d = d4.w, b = d >> 8;
            int pos = atomicAdd(&cur[b], 1);
            if (pos < CAP_SUB)
                arena[(size_t)(b * NSUB + j) * CAP_SUB + pos] = ((uint32_t)(d & 255) << 18) | (uint32_t)s4.w;
        }
    }
}

// ---- bucket-local counting sort (LDS) + dinv + bf16 xs prescale -------------
// Emits block-local degree-sorted permutation:
//   binfo2[b*256 + g*64 + slot] = nib<<23 | beg<<10 | len   (nib in [0,64))
// Scan over the 256 per-node counts is wave-shuffle based (2 barriers).

__global__ void bucket_sort(uint32_t* __restrict__ arena, const int* __restrict__ bcnt,
                            const float* __restrict__ x, float* __restrict__ dinv,
                            uint32_t* __restrict__ binfo2, uint16_t* __restrict__ xs) {
    __shared__ uint32_t stg[STG_CAP];
    __shared__ int scnt[NSUB];
    __shared__ int h[256];
    __shared__ int cur[256];
    __shared__ float dsh[256];
    __shared__ int dh[256];                       // 4 groups x 64 degree bins
    __shared__ int wsum[4];
    int b = blockIdx.x, t = threadIdx.x;
    int base = b * 256;
    if (t < NSUB) {
        int c = bcnt[(b * NSUB + t) * 16];
        scnt[t] = (c > CAP_SUB) ? CAP_SUB : c;
    }
    h[t] = 0;
    dh[t] = 0;
    __syncthreads();
    int off = 0;
    #pragma unroll
    for (int j = 0; j < NSUB; ++j) {
        int len = scnt[j];
        const uint32_t* sp = arena + (size_t)(b * NSUB + j) * CAP_SUB;
        for (int k = t; k < len; k += 256) stg[off + k] = sp[k];
        off += len;
    }
    int nb = off;
    __syncthreads();
    for (int k = t; k < nb; k += 256) atomicAdd(&h[stg[k] >> 18], 1);
    __syncthreads();
    int myh = h[t];
    int g64 = t >> 6, lane = t & 63;
    // wave-level inclusive scan of myh
    int inc = myh;
    #pragma unroll
    for (int o = 1; o < 64; o <<= 1) {
        int u = __shfl_up(inc, o);
        if (lane >= o) inc += u;
    }
    if (lane == 63) wsum[g64] = inc;
    __syncthreads();
    int woff = 0;
    #pragma unroll
    for (int wv = 0; wv < 4; ++wv) woff += (wv < g64) ? wsum[wv] : 0;
    int excl = inc + woff - myh;
    float dv = rsqrtf(1.0f + (float)myh);           // +1 self-loop
    dinv[base + t] = dv;
    dsh[t] = dv;
    cur[t] = excl;
    // group-local (64-node) degree histogram -> rank
    int dbin = (myh > 63) ? 63 : myh;
    atomicAdd(&dh[g64 * 64 + dbin], 1);
    __syncthreads();
    {   // each wave scans its own group's 64 bins (exclusive)
        int v = dh[g64 * 64 + lane];
        int inc2 = v;
        #pragma unroll
        for (int o = 1; o < 64; o <<= 1) {
            int u = __shfl_up(inc2, o);
            if (lane >= o) inc2 += u;
        }
        dh[g64 * 64 + lane] = inc2 - v;
    }
    __syncthreads();
    {
        int slot = atomicAdd(&dh[g64 * 64 + dbin], 1);   // rank within group
        int lc = (myh > 1023) ? 1023 : myh;
        binfo2[base + g64 * 64 + slot] =
            ((uint32_t)lane << 23) | ((uint32_t)excl << 10) | (uint32_t)lc;
    }
    uint32_t* wp = arena + (size_t)b * BROW;
    for (int k = t; k < nb; k += 256) {
        uint32_t w = stg[k];
        int d = w >> 18;
        int pos = atomicAdd(&cur[d], 1);
        wp[pos] = w & 0x3FFFF;
    }
    // fused bf16 prescale
    for (int idx = t; idx < 256 * 16; idx += 256) {
        int n = idx >> 4, k = idx & 15;
        float val = (k < IN_DIM) ? x[(size_t)(base + n) * IN_DIM + k] * dsh[n] : 0.0f;
        xs[(size_t)(base + n) * 16 + k] = f2bf(val);
    }
}

// ---- fused layer 1: gather xs + dense W1 + ReLU -> zs (bf16) ----------------
// block = 256 thr = 64 nodes; degree-balanced via block-local binfo2 slots.

__global__ void agg1_dense1(const uint16_t* __restrict__ xs, const uint32_t* __restrict__ arena,
                            const uint32_t* __restrict__ binfo2, const float* __restrict__ dinv,
                            const float* __restrict__ W1, const float* __restrict__ b1,
                            uint16_t* __restrict__ zs) {
    __shared__ float ash[64 * 12];
    __shared__ float w[IN_DIM * HIDDEN];
    int t = threadIdx.x;
    int base = blockIdx.x * 64;
    for (int j = t; j < IN_DIM * HIDDEN; j += 256) w[j] = W1[j];

    int idx = t >> 2;                                 // slot 0..63 (degree-sorted)
    uint32_t wrd = binfo2[base + idx];
    int nib = (int)(wrd >> 23);                       // 0..63, block-local
    int beg = (int)((wrd >> 10) & 0x1FFF);
    int len = (int)(wrd & 0x3FF);
    int n = base + nib;
    int q = t & 1, g = (t >> 1) & 1;
    const uint32_t* ep = arena + (size_t)(n >> 8) * BROW + beg;
    const uint4* Xv = reinterpret_cast<const uint4*>(xs);   // 2 uint4/row
    float a[8];
    #pragma unroll
    for (int j = 0; j < 8; ++j) a[j] = 0.0f;
    if (g == 0) {                                           // self-loop
        uint4 v = Xv[(size_t)n * 2 + q];
        a[0] += bf_lo(v.x); a[1] += bf_hi(v.x);
        a[2] += bf_lo(v.y); a[3] += bf_hi(v.y);
        a[4] += bf_lo(v.z); a[5] += bf_hi(v.z);
        a[6] += bf_lo(v.w); a[7] += bf_hi(v.w);
    }
    for (int i = g; i < len; i += 2) {
        int si = (int)ep[i];
        uint4 v = Xv[(size_t)si * 2 + q];
        a[0] += bf_lo(v.x); a[1] += bf_hi(v.x);
        a[2] += bf_lo(v.y); a[3] += bf_hi(v.y);
        a[4] += bf_lo(v.z); a[5] += bf_hi(v.z);
        a[6] += bf_lo(v.w); a[7] += bf_hi(v.w);
    }
    #pragma unroll
    for (int j = 0; j < 8; ++j) a[j] += __shfl_xor(a[j], 2);
    if (g == 0) {
        if (q == 0) {
            #pragma unroll
            for (int j = 0; j < 8; ++j) ash[nib * 12 + j] = a[j];
        } else {
            #pragma unroll
            for (int j = 0; j < 4; ++j) ash[nib * 12 + 8 + j] = a[j];  // cols 8..11
        }
    }
    __syncthreads();

    // dense: thread t -> node t>>2 (natural order), col-oct (t&3)*8
    int dn_i = t >> 2, c0 = (t & 3) * 8;
    int node = base + dn_i;
    float s[8];
    #pragma unroll
    for (int j = 0; j < 8; ++j) s[j] = 0.0f;
    #pragma unroll
    for (int k = 0; k < IN_DIM; ++k) {
        float ak = ash[dn_i * 12 + k];
        #pragma unroll
        for (int j = 0; j < 8; ++j) s[j] += ak * w[k * HIDDEN + c0 + j];
    }
    float dvv = dinv[node];
    uint32_t pk[4];
    #pragma unroll
    for (int j = 0; j < 4; ++j) {
        float v0 = fmaxf(dvv * s[2 * j] + b1[c0 + 2 * j], 0.0f) * dvv;
        float v1 = fmaxf(dvv * s[2 * j + 1] + b1[c0 + 2 * j + 1], 0.0f) * dvv;
        pk[j] = (uint32_t)f2bf(v0) | ((uint32_t)f2bf(v1) << 16);
    }
    reinterpret_cast<uint4*>(zs)[(size_t)node * 4 + (t & 3)] =
        make_uint4(pk[0], pk[1], pk[2], pk[3]);
}

// ---- fused layer 2: gather zs + dense W2 + ReLU + run-reduce pool -----------
// block = 256 thr = 64 nodes; pool = single serial 64-row run-reduce by 32
// column-threads (uniform branch, conflict-free LDS) -> ~6x fewer atomics.

__global__ void agg2_dense2_pool(const uint16_t* __restrict__ zs, const uint32_t* __restrict__ arena,
                                 const uint32_t* __restrict__ binfo2, const float* __restrict__ dinv,
                                 const float* __restrict__ W2, const float* __restrict__ b2,
                                 const int* __restrict__ batch, float* __restrict__ pooled) {
    __shared__ float vsh[64 * 33];
    __shared__ float w[HIDDEN * HIDDEN];
    __shared__ int bsh[64];
    int t = threadIdx.x;
    int base = blockIdx.x * 64;
    for (int j = t; j < HIDDEN * HIDDEN; j += 256) w[j] = W2[j];
    if (t < 64) bsh[t] = batch[base + t];

    int idx = t >> 2;                                 // slot 0..63 (degree-sorted)
    uint32_t wrd = binfo2[base + idx];
    int nib = (int)(wrd >> 23);                       // 0..63, block-local
    int beg = (int)((wrd >> 10) & 0x1FFF);
    int len = (int)(wrd & 0x3FF);
    int n = base + nib;
    int q = t & 3;
    const uint32_t* ep = arena + (size_t)(n >> 8) * BROW + beg;
    const uint4* Zv = reinterpret_cast<const uint4*>(zs);   // 4 uint4/row
    float a[8];
    {                                                       // self-loop init
        uint4 v = Zv[(size_t)n * 4 + q];
        a[0] = bf_lo(v.x); a[1] = bf_hi(v.x);
        a[2] = bf_lo(v.y); a[3] = bf_hi(v.y);
        a[4] = bf_lo(v.z); a[5] = bf_hi(v.z);
        a[6] = bf_lo(v.w); a[7] = bf_hi(v.w);
    }
    for (int i = 0; i < len; ++i) {
        int si = (int)ep[i];
        uint4 v = Zv[(size_t)si * 4 + q];
        a[0] += bf_lo(v.x); a[1] += bf_hi(v.x);
        a[2] += bf_lo(v.y); a[3] += bf_hi(v.y);
        a[4] += bf_lo(v.z); a[5] += bf_hi(v.z);
        a[6] += bf_lo(v.w); a[7] += bf_hi(v.w);
    }
    #pragma unroll
    for (int j = 0; j < 8; ++j) vsh[nib * 33 + q * 8 + j] = a[j];
    __syncthreads();

    // dense: thread t -> node t>>2 (natural order), col-oct (t&3)*8
    int dn_i = t >> 2, c0 = (t & 3) * 8;
    int node = base + dn_i;
    float s[8];
    #pragma unroll
    for (int j = 0; j < 8; ++j) s[j] = 0.0f;
    #pragma unroll
    for (int k = 0; k < HIDDEN; ++k) {
        float ak = vsh[dn_i * 33 + k];
        #pragma unroll
        for (int j = 0; j < 8; ++j) s[j] += ak * w[k * HIDDEN + c0 + j];
    }
    float dvv = dinv[node];
    float v[8];
    #pragma unroll
    for (int j = 0; j < 8; ++j) v[j] = fmaxf(dvv * s[j] + b2[c0 + j], 0.0f);
    __syncthreads();
    #pragma unroll
    for (int j = 0; j < 8; ++j) vsh[dn_i * 33 + c0 + j] = v[j];
    __syncthreads();

    // pool: 32 column-threads run-reduce over all 64 rows (batch sorted,
    // branch uniform across lanes since bsh[j] is shared).
    if (t < 32) {
        int col = t;
        float run = vsh[0 * 33 + col];
        int cur = bsh[0];
        #pragma unroll 8
        for (int j = 1; j < 64; ++j) {
            int bg = bsh[j];
            float vv = vsh[j * 33 + col];
            if (bg == cur) run += vv;
            else {
                fatomic_add(&pooled[(size_t)cur * HIDDEN + col], run);
                run = vv;
                cur = bg;
            }
        }
        fatomic_add(&pooled[(size_t)cur * HIDDEN + col], run);
    }
}

// ---- final linear (graph counts via binary search on sorted batch) ----------

__global__ void final_k(const float* __restrict__ pooled, const int* __restrict__ batch,
                        const float* __restrict__ Wlin, const float* __restrict__ blin,
                        float* __restrict__ out) {
    int g = blockIdx.x * blockDim.x + threadIdx.x;
    if (g < N_GRAPHS) {
        int lo = 0, hi = N_NODES;
        while (lo < hi) { int mid = (lo + hi) >> 1; if (batch[mid] < g) lo = mid + 1; else hi = mid; }
        int first = lo;
        lo = 0; hi = N_NODES;
        while (lo < hi) { int mid = (lo + hi) >> 1; if (batch[mid] <= g) lo = mid + 1; else hi = mid; }
        float cc = (float)(lo - first);
        if (cc < 1.0f) cc = 1.0f;
        float s = 0.0f;
        #pragma unroll
        for (int c = 0; c < HIDDEN; ++c) s += pooled[(size_t)g * HIDDEN + c] * Wlin[c];
        out[g] = s / cc + blin[0];
    }
}

// ---- launch -------------------------------------------------------------------

extern "C" void kernel_launch(void* const* d_in, const int* in_sizes, int n_in,
                              void* d_out, int out_size, void* d_ws, size_t ws_size,
                              hipStream_t stream) {
    const float* x     = (const float*)d_in[0];
    const int*   ei    = (const int*)d_in[1];
    const int*   batch = (const int*)d_in[2];
    const float* W1    = (const float*)d_in[3];
    const float* b1    = (const float*)d_in[4];
    const float* W2    = (const float*)d_in[5];
    const float* b2    = (const float*)d_in[6];
    const float* Wlin  = (const float*)d_in[7];
    const float* blin  = (const float*)d_in[8];
    float* out = (float*)d_out;

    const int* src = ei;
    const int* dst = ei + N_EDGES;

    const size_t N = N_NODES;
    float*    F      = (float*)d_ws;
    uint16_t* zs     = (uint16_t*)F;                       // 32 bf16/node = 8N words
    uint16_t* xs     = (uint16_t*)(F + 8 * N);             // 16 bf16/node = 8N words
    float*    dinv   = F + 16 * N;                         // N
    uint32_t* binfo2 = (uint32_t*)(dinv + N);              // N
    int*      bcnt   = (int*)(binfo2 + N);                 // 1024*8*16  -- zeroed
    float*    pooled = (float*)(bcnt + NBUCKET * NSUB * 16); // G*32     -- zeroed
    uint32_t* arena  = (uint32_t*)(pooled + (size_t)N_GRAPHS * HIDDEN); // NBUCKET*BROW

    size_t zbytes = ((size_t)NBUCKET * NSUB * 16 + (size_t)N_GRAPHS * HIDDEN) * sizeof(int);
    hipMemsetAsync(bcnt, 0, zbytes, stream);

    passA<<<PA_BLOCKS, PA_THREADS, 0, stream>>>(src, dst, bcnt, arena);
    bucket_sort<<<NBUCKET, 256, 0, stream>>>(arena, bcnt, x, dinv, binfo2, xs);
    agg1_dense1<<<N_NODES / 64, 256, 0, stream>>>(xs, arena, binfo2, dinv, W1, b1, zs);
    agg2_dense2_pool<<<N_NODES / 64, 256, 0, stream>>>(zs, arena, binfo2, dinv, W2, b2, batch, pooled);
    final_k<<<(N_GRAPHS + 255) / 256, 256, 0, stream>>>(pooled, batch, Wlin, blin, out);
}